// Round 12
// baseline (109.100 us; speedup 1.0000x reference)
//
#include <hip/hip_runtime.h>
#include <hip/hip_bf16.h>
#include <stdint.h>

typedef __attribute__((ext_vector_type(4))) float f32x4;
typedef __attribute__((ext_vector_type(8))) __bf16 bf16x8;
typedef __attribute__((ext_vector_type(4))) __bf16 bf16x4;

#define DEVI __device__ __forceinline__

static constexpr int S_  = 2048;
static constexpr int D_  = 1024;
static constexpr int H_  = 16;
static constexpr int HD_ = 64;
static constexpr int M_  = 2 * S_;   // B*S = 4096 token rows
static constexpr float SCL2 = 0.18033688f;  // 0.125 * log2(e)

DEVI void gload_lds16(const void* gsrc, void* ldst) {
  __builtin_amdgcn_global_load_lds(
      (__attribute__((address_space(1))) void*)(void*)gsrc,
      (__attribute__((address_space(3))) void*)ldst, 16, 0, 0);
}

DEVI float fexp2(float x) {
  float r;
  asm("v_exp_f32 %0, %1" : "=v"(r) : "v"(x));
  return r;
}

// One fused conversion kernel: x + 4 weights fp32->bf16, plus RoPE table.
__global__ __launch_bounds__(256) void cvt_all_kernel(
    const float* __restrict__ x, const float* __restrict__ wq,
    const float* __restrict__ wk, const float* __restrict__ wv,
    const float* __restrict__ wo,
    __bf16* __restrict__ xb, __bf16* __restrict__ wqb,
    __bf16* __restrict__ wkb, __bf16* __restrict__ wvb,
    __bf16* __restrict__ wob, float* __restrict__ tab) {
  int blk = blockIdx.x;
  if (blk < 8192) {
    int i = blk * 256 + threadIdx.x;     // float4 index
    const float* src; __bf16* dst; int off;
    if (i < (1 << 20))                      { src = x;  dst = xb;  off = 0; }
    else if (i < (1 << 20) + (1 << 18))     { src = wq; dst = wqb; off = (1 << 20); }
    else if (i < (1 << 20) + 2 * (1 << 18)) { src = wk; dst = wkb; off = (1 << 20) + (1 << 18); }
    else if (i < (1 << 20) + 3 * (1 << 18)) { src = wv; dst = wvb; off = (1 << 20) + 2 * (1 << 18); }
    else                                    { src = wo; dst = wob; off = (1 << 20) + 3 * (1 << 18); }
    int j = i - off;
    float4 v = reinterpret_cast<const float4*>(src)[j];
    bf16x4 o;
    o[0] = (__bf16)v.x; o[1] = (__bf16)v.y; o[2] = (__bf16)v.z; o[3] = (__bf16)v.w;
    reinterpret_cast<bf16x4*>(dst)[j] = o;
  } else {
    int i = (blk - 8192) * 256 + threadIdx.x;   // 0..65535 = S*32
    int s = i >> 5, f = i & 31;
    float freq = powf(10000.0f, -(float)(2 * f) / (float)HD_);
    float ang = (float)s * freq;
    tab[2 * i]     = cosf(ang);
    tab[2 * i + 1] = sinf(ang);
  }
}

// ---------------------------------------------------------------------------
// QKV GEMM: m97 128x128 BK=32 structure, 512-thread / 8-wave blocks
// (wave grid 2M x 4N). Proven round-11 kernel, unchanged.
// ---------------------------------------------------------------------------
__global__ __launch_bounds__(512, 6) void gemm_qkv(
    const __bf16* __restrict__ A, const __bf16* __restrict__ W0,
    const __bf16* __restrict__ W1, const __bf16* __restrict__ W2,
    __bf16* __restrict__ Cq, __bf16* __restrict__ Ck, __bf16* __restrict__ Cvt,
    const float* __restrict__ tab) {
  __shared__ __attribute__((aligned(16))) __bf16 As[128 * 32];
  __shared__ __attribute__((aligned(16))) __bf16 Bs[128 * 32];
  const int tid  = threadIdx.x;
  const int lane = tid & 63;
  const int wv   = tid >> 6;           // 0..7
  const int wr   = wv >> 2;            // 0..1 (M strip of 64)
  const int wc   = wv & 3;             // 0..3 (N strip of 32)
  const int m0 = blockIdx.x * 128;
  const int n0 = blockIdx.y * 128;
  const int z  = blockIdx.z;
  const __bf16* W = (z == 0) ? W0 : (z == 1 ? W1 : W2);
  const int arow = lane & 15;
  const int kgrp = (lane >> 4) * 8;

  f32x4 acc[4][2];
#pragma unroll
  for (int i = 0; i < 4; i++)
#pragma unroll
    for (int j = 0; j < 2; j++) acc[i][j] = f32x4{0.f, 0.f, 0.f, 0.f};

  for (int k0 = 0; k0 < 1024; k0 += 32) {
    __syncthreads();
    {
      int c   = wv * 64 + lane;        // chunk 0..511 (whole tile)
      int row = c >> 2;
      int kc  = (c & 3) * 8;
      gload_lds16(A + (size_t)(m0 + row) * 1024 + k0 + kc, As + wv * 512);
      gload_lds16(W + (size_t)(n0 + row) * 1024 + k0 + kc, Bs + wv * 512);
    }
    asm volatile("s_waitcnt vmcnt(0)" ::: "memory");
    __syncthreads();
    bf16x8 af[4], bw[2];
#pragma unroll
    for (int i = 0; i < 4; i++)
      af[i] = *reinterpret_cast<const bf16x8*>(As + (wr * 64 + i * 16 + arow) * 32 + kgrp);
#pragma unroll
    for (int j = 0; j < 2; j++)
      bw[j] = *reinterpret_cast<const bf16x8*>(Bs + (wc * 32 + j * 16 + arow) * 32 + kgrp);
#pragma unroll
    for (int i = 0; i < 4; i++)
#pragma unroll
      for (int j = 0; j < 2; j++)
        acc[i][j] = __builtin_amdgcn_mfma_f32_16x16x32_bf16(af[i], bw[j], acc[i][j], 0, 0, 0);
  }

  // epilogue. C/D layout: col = lane&15 (n), row = (lane>>4)*4 + r (m)
  if (z == 2) {
#pragma unroll
    for (int i = 0; i < 4; i++) {
      int m = m0 + wr * 64 + i * 16 + (lane >> 4) * 4;
      int bb = m >> 11, srow = m & (S_ - 1);
#pragma unroll
      for (int j = 0; j < 2; j++) {
        int n = n0 + wc * 32 + j * 16 + arow;
        int h = n >> 6, d = n & 63;
        bf16x4 o4;
#pragma unroll
        for (int r = 0; r < 4; r++) o4[r] = (__bf16)acc[i][j][r];
        *reinterpret_cast<bf16x4*>(
            Cvt + ((size_t)(bb * H_ + h) * HD_ + d) * S_ + srow) = o4;
      }
    }
  } else {
#pragma unroll
    for (int i = 0; i < 4; i++) {
#pragma unroll
      for (int j = 0; j < 2; j++) {
#pragma unroll
        for (int r = 0; r < 4; r++) {
          int m = m0 + wr * 64 + i * 16 + (lane >> 4) * 4 + r;
          int n = n0 + wc * 32 + j * 16 + arow;
          float v = acc[i][j][r];
          int bb = m >> 11, srow = m & (S_ - 1);
          int h = n >> 6, d = n & 63;
          size_t oidx = ((size_t)(bb * H_ + h) * S_ + srow) * HD_ + d;
          float other = __shfl_xor(v, 1, 64);   // n bit0 == lane bit0
          int fq = d >> 1;
          float2 cssn = *reinterpret_cast<const float2*>(tab + (srow * 32 + fq) * 2);
          float rv = (d & 1) ? (other * cssn.y + v * cssn.x)
                             : (v * cssn.x - other * cssn.y);
          if (z == 0) rv *= SCL2;   // pre-scale Q: logits in exp2 domain
          ((z == 0) ? Cq : Ck)[oidx] = (__bf16)rv;
        }
      }
    }
  }
}

// ---------------------------------------------------------------------------
// O-projection: tile 128x64, 512-thread / 8-wave blocks. Proven round-11
// kernel, unchanged.
// ---------------------------------------------------------------------------
__global__ __launch_bounds__(512, 4) void gemm_bt0(
    const __bf16* __restrict__ A, const __bf16* __restrict__ W0,
    float* __restrict__ Cf) {
  __shared__ __attribute__((aligned(16))) __bf16 As[128 * 32];
  __shared__ __attribute__((aligned(16))) __bf16 Bs[64 * 32];
  const int tid  = threadIdx.x;
  const int lane = tid & 63;
  const int wv   = tid >> 6;
  const int wr   = wv >> 1;            // 0..3 (M strip of 32)
  const int wc   = wv & 1;             // 0..1 (N strip of 32)
  const int m0 = blockIdx.x * 128;
  const int n0 = blockIdx.y * 64;
  const int arow = lane & 15;
  const int kgrp = (lane >> 4) * 8;

  f32x4 acc[2][2];
#pragma unroll
  for (int i = 0; i < 2; i++)
#pragma unroll
    for (int j = 0; j < 2; j++) acc[i][j] = f32x4{0.f, 0.f, 0.f, 0.f};

  for (int k0 = 0; k0 < 1024; k0 += 32) {
    __syncthreads();
    {
      int c   = wv * 64 + lane;        // 0..511 -> A rows 0..127
      int row = c >> 2;
      int kc  = (c & 3) * 8;
      gload_lds16(A + (size_t)(m0 + row) * 1024 + k0 + kc, As + wv * 512);
      if (wv < 4)                      // 0..255 -> B rows 0..63
        gload_lds16(W0 + (size_t)(n0 + row) * 1024 + k0 + kc, Bs + wv * 512);
    }
    asm volatile("s_waitcnt vmcnt(0)" ::: "memory");
    __syncthreads();
    bf16x8 af[2], bw[2];
#pragma unroll
    for (int i = 0; i < 2; i++)
      af[i] = *reinterpret_cast<const bf16x8*>(As + (wr * 32 + i * 16 + arow) * 32 + kgrp);
#pragma unroll
    for (int j = 0; j < 2; j++)
      bw[j] = *reinterpret_cast<const bf16x8*>(Bs + (wc * 32 + j * 16 + arow) * 32 + kgrp);
#pragma unroll
    for (int i = 0; i < 2; i++)
#pragma unroll
      for (int j = 0; j < 2; j++)
        acc[i][j] = __builtin_amdgcn_mfma_f32_16x16x32_bf16(af[i], bw[j], acc[i][j], 0, 0, 0);
  }

#pragma unroll
  for (int i = 0; i < 2; i++)
#pragma unroll
    for (int j = 0; j < 2; j++)
#pragma unroll
      for (int r = 0; r < 4; r++) {
        int m = m0 + wr * 32 + i * 16 + (lane >> 4) * 4 + r;
        int n = n0 + wc * 32 + j * 16 + arow;
        Cf[(size_t)m * D_ + n] = acc[i][j][r];
      }
}

// ---------------------------------------------------------------------------
// Flash attention, causal. Grid: (bh=32, pr=16). 4 waves x 16 q-rows, paired
// q-tiles (pr, 31-pr), KVBLK=128. NEW: lag-1 softmax/PV pipeline (T15) --
// per iter: issue QK^T(kt+1) MFMA (independent), then softmax+PV(kt) on
// scores computed one iter earlier => no QK->softmax wait on critical path.
// K triple-buffered, V double-buffered (80 KB LDS, 2 blocks/CU).
// vmcnt protocol: prologue stages K0,V0,K1,V1,K2 then vmcnt(8) (K0,V0,K1
// landed). TAIL(kt) stages K(kt+3)->Ks[(kt+3)%3], V(kt+2)->Vs[kt&1], then
// vmcnt(8) => K(kt+2),V(kt+1) landed for the next body. Clamped duplicate
// stages keep per-TAIL load count uniform (8). Last TAIL drains vmcnt(0).
// ---------------------------------------------------------------------------
__global__ __launch_bounds__(256, 2) void attn_kernel(
    const __bf16* __restrict__ Q, const __bf16* __restrict__ K,
    const __bf16* __restrict__ Vt, __bf16* __restrict__ O) {
  __shared__ __attribute__((aligned(16))) __bf16 Ks[3][128 * 64];
  __shared__ __attribute__((aligned(16))) __bf16 Vs[2][64 * 128];
  const int tid = threadIdx.x, lane = tid & 63, wv = tid >> 6;
  const int bh = blockIdx.x;   // linear id stride 32 => all pr of a bh share an XCD
  const int pr = blockIdx.y;
  const int b = bh >> 4, h = bh & 15;
  const __bf16* Qb  = Q  + (size_t)bh * S_ * HD_;
  const __bf16* Kb  = K  + (size_t)bh * S_ * HD_;
  const __bf16* Vtb = Vt + (size_t)bh * HD_ * S_;
  const int arow = lane & 15, g = lane >> 4;

#define STAGE_K(K0, DST)                                                      \
  do {                                                                        \
    _Pragma("unroll") for (int j = 0; j < 4; ++j) {                           \
      int c = (wv * 4 + j) * 64 + lane;                                       \
      int rowk = c >> 3, qqk = c & 7;                                         \
      int qsk = qqk ^ (rowk & 7);                                             \
      int ctp = rowk >> 4, rw = rowk & 15;                                    \
      int kph = ((ctp & 4) << 4) + ((ctp & 2) << 4) + ((ctp & 1) << 2)        \
                + ((rw >> 2) << 3) + (rw & 3);                                \
      gload_lds16(Kb + (size_t)((K0) + kph) * HD_ + qsk * 8,                  \
                  (DST) + (size_t)(wv * 4 + j) * 512);                        \
    }                                                                         \
  } while (0)

#define STAGE_V(K0, DST)                                                      \
  do {                                                                        \
    _Pragma("unroll") for (int j = 0; j < 4; ++j) {                           \
      int c = (wv * 4 + j) * 64 + lane;                                       \
      int rowv = c >> 4, qqv = c & 15;                                        \
      int qsv = qqv ^ (rowv & 7);                                             \
      gload_lds16(Vtb + (size_t)rowv * S_ + (K0) + qsv * 8,                   \
                  (DST) + (size_t)(wv * 4 + j) * 512);                        \
    }                                                                         \
  } while (0)

  // QK^T into SC: D[key][q], 16 MFMA over 128 keys
#define QKT(KC, SC)                                                           \
  do {                                                                        \
    __builtin_amdgcn_s_setprio(1);                                            \
    _Pragma("unroll") for (int ct = 0; ct < 8; ct++) {                        \
      (SC)[ct] = f32x4{0.f, 0.f, 0.f, 0.f};                                   \
      int L = ct * 16 + arow;                                                 \
      _Pragma("unroll") for (int j2 = 0; j2 < 2; j2++) {                      \
        int byt = (L * 128 + j2 * 64 + g * 16) ^ ((L & 7) << 4);              \
        bf16x8 kb = *reinterpret_cast<const bf16x8*>((const char*)(KC) + byt);\
        (SC)[ct] = __builtin_amdgcn_mfma_f32_16x16x32_bf16(kb, aq[j2],        \
                                                           (SC)[ct], 0, 0, 0);\
      }                                                                       \
    }                                                                         \
    __builtin_amdgcn_s_setprio(0);                                            \
  } while (0)

  // softmax + PV for tile KT using scores SC and V-buffer VC
#define SMPV(KT, SC, VC)                                                      \
  do {                                                                        \
    const int k0_ = (KT) * 128;                                               \
    if ((KT) == nkv - 1) {                                                    \
      _Pragma("unroll") for (int ct = 0; ct < 8; ct++) {                      \
        int kb0 = k0_ + ((ct & 4) << 4) + ((ct & 2) << 4) + ((ct & 1) << 2)   \
                  + g * 8;                                                    \
        _Pragma("unroll") for (int r = 0; r < 4; r++)                         \
          if (kb0 + r > qg) (SC)[ct][r] = -1e30f;                             \
      }                                                                       \
    }                                                                         \
    float mx = -1e30f;                                                        \
    _Pragma("unroll") for (int ct = 0; ct < 8; ct++)                          \
      _Pragma("unroll") for (int r = 0; r < 4; r++)                           \
        mx = fmaxf(mx, (SC)[ct][r]);                                          \
    mx = fmaxf(mx, __shfl_xor(mx, 16, 64));                                   \
    mx = fmaxf(mx, __shfl_xor(mx, 32, 64));                                   \
    bool noskip = !__all(mx <= mrow + 11.0f);                                 \
    if (noskip) {                                                             \
      float mnew = fmaxf(mrow, mx);                                           \
      float corr = fexp2(mrow - mnew);                                        \
      mrow = mnew;                                                            \
      lrow *= corr;                                                           \
      _Pragma("unroll") for (int dt = 0; dt < 4; dt++)                        \
        _Pragma("unroll") for (int r = 0; r < 4; r++) po[dt][r] *= corr;      \
    }                                                                         \
    float rs = 0.f;                                                           \
    _Pragma("unroll") for (int ct = 0; ct < 8; ct++)                          \
      _Pragma("unroll") for (int r = 0; r < 4; r++) {                         \
        float e = fexp2((SC)[ct][r] - mrow);                                  \
        (SC)[ct][r] = e;                                                      \
        rs += e;                                                              \
      }                                                                       \
    rs += __shfl_xor(rs, 16, 64);                                             \
    rs += __shfl_xor(rs, 32, 64);                                             \
    lrow += rs;                                                               \
    bf16x8 pb[4];                                                             \
    _Pragma("unroll") for (int h2 = 0; h2 < 2; h2++)                          \
      _Pragma("unroll") for (int j2 = 0; j2 < 2; j2++)                        \
        _Pragma("unroll") for (int r = 0; r < 4; r++) {                       \
          pb[h2 * 2 + j2][r]     = (__bf16)(SC)[h2 * 4 + 2 * j2][r];          \
          pb[h2 * 2 + j2][4 + r] = (__bf16)(SC)[h2 * 4 + 2 * j2 + 1][r];      \
        }                                                                     \
    __builtin_amdgcn_s_setprio(1);                                            \
    _Pragma("unroll") for (int dt = 0; dt < 4; dt++) {                        \
      int d = dt * 16 + arow;                                                 \
      _Pragma("unroll") for (int jj = 0; jj < 4; jj++) {                      \
        int byv = (d * 256 + jj * 64 + g * 16) ^ ((d & 7) << 4);              \
        bf16x8 vb = *reinterpret_cast<const bf16x8*>((const char*)(VC) + byv);\
        po[dt] = __builtin_amdgcn_mfma_f32_16x16x32_bf16(vb, pb[jj],          \
                                                         po[dt], 0, 0, 0);    \
      }                                                                       \
    }                                                                         \
    __builtin_amdgcn_s_setprio(0);                                            \
  } while (0)

  for (int seg = 0; seg < 2; ++seg) {
    const int qt = (seg == 0) ? pr : 31 - pr;   // 64-row q-tile index
    const int q0 = qt * 64;
    const int nkv = (qt >> 1) + 1;              // 128-key tiles
    const int qw = q0 + wv * 16;
    const int qg = qw + arow;                   // this thread's q-row

    bf16x8 aq[2];
#pragma unroll
    for (int j = 0; j < 2; j++)
      aq[j] = *reinterpret_cast<const bf16x8*>(
          Qb + (size_t)(qw + arow) * HD_ + j * 32 + g * 8);

    f32x4 po[4];
#pragma unroll
    for (int dt = 0; dt < 4; dt++) po[dt] = f32x4{0.f, 0.f, 0.f, 0.f};
    float mrow = -1e30f, lrow = 0.f;
    f32x4 scA[8], scB[8];

    // prologue: K0,V0,K1,V1,K2 (clamped); vmcnt(8) => K0,V0,K1 landed
    STAGE_K(0, Ks[0]);
    STAGE_V(0, Vs[0]);
    {
      int t1 = (nkv > 1) ? 128 : 0;
      STAGE_K(t1, Ks[1]);
      STAGE_V(t1, Vs[1]);
      int t2 = (nkv > 2) ? 256 : t1;
      STAGE_K(t2, Ks[2]);
    }
    asm volatile("s_waitcnt vmcnt(8)" ::: "memory");
    __builtin_amdgcn_s_barrier();

    QKT(Ks[0], scA);

    for (int kt = 0; kt < nkv; kt += 2) {
      // ---- body A: tile kt (even; V parity 0) ----
      if (kt + 1 < nkv) QKT(Ks[(kt + 1) % 3], scB);
      SMPV(kt, scA, Vs[0]);
      __builtin_amdgcn_s_barrier();
      if (kt < nkv - 1) {
        int tk = (kt + 3 <= nkv - 1) ? kt + 3 : nkv - 1;
        int tv = (kt + 2 <= nkv - 1) ? kt + 2 : nkv - 1;
        STAGE_K(tk * 128, Ks[(kt + 3) % 3]);
        STAGE_V(tv * 128, Vs[0]);
        asm volatile("s_waitcnt vmcnt(8)" ::: "memory");
      } else {
        asm volatile("s_waitcnt vmcnt(0)" ::: "memory");
      }
      __builtin_amdgcn_s_barrier();

      // ---- body B: tile kt+1 (odd; V parity 1) ----
      if (kt + 1 < nkv) {
        if (kt + 2 < nkv) QKT(Ks[(kt + 2) % 3], scA);
        SMPV(kt + 1, scB, Vs[1]);
        __builtin_amdgcn_s_barrier();
        if (kt + 1 < nkv - 1) {
          int tk = (kt + 4 <= nkv - 1) ? kt + 4 : nkv - 1;
          int tv = (kt + 3 <= nkv - 1) ? kt + 3 : nkv - 1;
          STAGE_K(tk * 128, Ks[(kt + 4) % 3]);
          STAGE_V(tv * 128, Vs[1]);
          asm volatile("s_waitcnt vmcnt(8)" ::: "memory");
        } else {
          asm volatile("s_waitcnt vmcnt(0)" ::: "memory");
        }
        __builtin_amdgcn_s_barrier();
      }
    }

    float inv = __builtin_amdgcn_rcpf(lrow);
#pragma unroll
    for (int dt = 0; dt < 4; dt++) {
      bf16x4 o4;
#pragma unroll
      for (int r = 0; r < 4; r++) o4[r] = (__bf16)(po[dt][r] * inv);
      *reinterpret_cast<bf16x4*>(
          O + (size_t)(b * S_ + qg) * D_ + h * HD_ + dt * 16 + g * 4) = o4;
    }
  }
#undef STAGE_K
#undef STAGE_V
#undef QKT
#undef SMPV
}

extern "C" void kernel_launch(void* const* d_in, const int* in_sizes, int n_in,
                              void* d_out, int out_size, void* d_ws, size_t ws_size,
                              hipStream_t stream) {
  const float* x  = (const float*)d_in[0];
  const float* wq = (const float*)d_in[1];
  const float* wk = (const float*)d_in[2];
  const float* wv = (const float*)d_in[3];
  const float* wo = (const float*)d_in[4];
  float* out = (float*)d_out;

  char* w = (char*)d_ws;
  __bf16* xb  = (__bf16*)(w);                    // 8 MB
  __bf16* wqb = (__bf16*)(w + (8u  << 20));      // 2 MB each
  __bf16* wkb = (__bf16*)(w + (10u << 20));
  __bf16* wvb = (__bf16*)(w + (12u << 20));
  __bf16* wob = (__bf16*)(w + (14u << 20));
  __bf16* qws = (__bf16*)(w + (16u << 20));      // 8 MB each
  __bf16* kws = (__bf16*)(w + (24u << 20));
  __bf16* vtw = (__bf16*)(w + (32u << 20));      // V, stored TRANSPOSED [bh][d][s]
  __bf16* aws = (__bf16*)(w + (40u << 20));      // attn out, [token][feature]
  float*  tab = (float*)(w + (48u << 20));       // 512 KB rope table

  cvt_all_kernel<<<8448, 256, 0, stream>>>(x, wq, wk, wv, wo,
                                           xb, wqb, wkb, wvb, wob, tab);
  gemm_qkv<<<dim3(32, 8, 3), 512, 0, stream>>>(xb, wqb, wkb, wvb,
                                               qws, kws, vtw, tab);
  attn_kernel<<<dim3(2 * H_, S_ / 128), 256, 0, stream>>>(qws, kws, vtw, aws);
  gemm_bt0<<<dim3(M_ / 128, D_ / 64), 512, 0, stream>>>(aws, wob, out);
}

// Round 13
// 107.068 us; speedup vs baseline: 1.0190x; 1.0190x over previous
//
#include <hip/hip_runtime.h>
#include <hip/hip_bf16.h>
#include <stdint.h>

typedef __attribute__((ext_vector_type(4))) float f32x4;
typedef __attribute__((ext_vector_type(8))) __bf16 bf16x8;
typedef __attribute__((ext_vector_type(4))) __bf16 bf16x4;

#define DEVI __device__ __forceinline__

static constexpr int S_  = 2048;
static constexpr int D_  = 1024;
static constexpr int H_  = 16;
static constexpr int HD_ = 64;
static constexpr int M_  = 2 * S_;   // B*S = 4096 token rows
static constexpr float SCL2 = 0.18033688f;  // 0.125 * log2(e)

DEVI void gload_lds16(const void* gsrc, void* ldst) {
  __builtin_amdgcn_global_load_lds(
      (__attribute__((address_space(1))) void*)(void*)gsrc,
      (__attribute__((address_space(3))) void*)ldst, 16, 0, 0);
}

DEVI float fexp2(float x) {
  float r;
  asm("v_exp_f32 %0, %1" : "=v"(r) : "v"(x));
  return r;
}

// One fused conversion kernel: x + 4 weights fp32->bf16, plus RoPE table.
__global__ __launch_bounds__(256) void cvt_all_kernel(
    const float* __restrict__ x, const float* __restrict__ wq,
    const float* __restrict__ wk, const float* __restrict__ wv,
    const float* __restrict__ wo,
    __bf16* __restrict__ xb, __bf16* __restrict__ wqb,
    __bf16* __restrict__ wkb, __bf16* __restrict__ wvb,
    __bf16* __restrict__ wob, float* __restrict__ tab) {
  int blk = blockIdx.x;
  if (blk < 8192) {
    int i = blk * 256 + threadIdx.x;     // float4 index
    const float* src; __bf16* dst; int off;
    if (i < (1 << 20))                      { src = x;  dst = xb;  off = 0; }
    else if (i < (1 << 20) + (1 << 18))     { src = wq; dst = wqb; off = (1 << 20); }
    else if (i < (1 << 20) + 2 * (1 << 18)) { src = wk; dst = wkb; off = (1 << 20) + (1 << 18); }
    else if (i < (1 << 20) + 3 * (1 << 18)) { src = wv; dst = wvb; off = (1 << 20) + 2 * (1 << 18); }
    else                                    { src = wo; dst = wob; off = (1 << 20) + 3 * (1 << 18); }
    int j = i - off;
    float4 v = reinterpret_cast<const float4*>(src)[j];
    bf16x4 o;
    o[0] = (__bf16)v.x; o[1] = (__bf16)v.y; o[2] = (__bf16)v.z; o[3] = (__bf16)v.w;
    reinterpret_cast<bf16x4*>(dst)[j] = o;
  } else {
    int i = (blk - 8192) * 256 + threadIdx.x;   // 0..65535 = S*32
    int s = i >> 5, f = i & 31;
    float freq = powf(10000.0f, -(float)(2 * f) / (float)HD_);
    float ang = (float)s * freq;
    tab[2 * i]     = cosf(ang);
    tab[2 * i + 1] = sinf(ang);
  }
}

// ---------------------------------------------------------------------------
// QKV GEMM: m97 128x128 BK=32 structure, 512-thread / 8-wave blocks
// (wave grid 2M x 4N). Proven round-11 kernel, unchanged.
// ---------------------------------------------------------------------------
__global__ __launch_bounds__(512, 6) void gemm_qkv(
    const __bf16* __restrict__ A, const __bf16* __restrict__ W0,
    const __bf16* __restrict__ W1, const __bf16* __restrict__ W2,
    __bf16* __restrict__ Cq, __bf16* __restrict__ Ck, __bf16* __restrict__ Cvt,
    const float* __restrict__ tab) {
  __shared__ __attribute__((aligned(16))) __bf16 As[128 * 32];
  __shared__ __attribute__((aligned(16))) __bf16 Bs[128 * 32];
  const int tid  = threadIdx.x;
  const int lane = tid & 63;
  const int wv   = tid >> 6;           // 0..7
  const int wr   = wv >> 2;            // 0..1 (M strip of 64)
  const int wc   = wv & 3;             // 0..3 (N strip of 32)
  const int m0 = blockIdx.x * 128;
  const int n0 = blockIdx.y * 128;
  const int z  = blockIdx.z;
  const __bf16* W = (z == 0) ? W0 : (z == 1 ? W1 : W2);
  const int arow = lane & 15;
  const int kgrp = (lane >> 4) * 8;

  f32x4 acc[4][2];
#pragma unroll
  for (int i = 0; i < 4; i++)
#pragma unroll
    for (int j = 0; j < 2; j++) acc[i][j] = f32x4{0.f, 0.f, 0.f, 0.f};

  for (int k0 = 0; k0 < 1024; k0 += 32) {
    __syncthreads();
    {
      int c   = wv * 64 + lane;        // chunk 0..511 (whole tile)
      int row = c >> 2;
      int kc  = (c & 3) * 8;
      gload_lds16(A + (size_t)(m0 + row) * 1024 + k0 + kc, As + wv * 512);
      gload_lds16(W + (size_t)(n0 + row) * 1024 + k0 + kc, Bs + wv * 512);
    }
    asm volatile("s_waitcnt vmcnt(0)" ::: "memory");
    __syncthreads();
    bf16x8 af[4], bw[2];
#pragma unroll
    for (int i = 0; i < 4; i++)
      af[i] = *reinterpret_cast<const bf16x8*>(As + (wr * 64 + i * 16 + arow) * 32 + kgrp);
#pragma unroll
    for (int j = 0; j < 2; j++)
      bw[j] = *reinterpret_cast<const bf16x8*>(Bs + (wc * 32 + j * 16 + arow) * 32 + kgrp);
#pragma unroll
    for (int i = 0; i < 4; i++)
#pragma unroll
      for (int j = 0; j < 2; j++)
        acc[i][j] = __builtin_amdgcn_mfma_f32_16x16x32_bf16(af[i], bw[j], acc[i][j], 0, 0, 0);
  }

  // epilogue. C/D layout: col = lane&15 (n), row = (lane>>4)*4 + r (m)
  if (z == 2) {
#pragma unroll
    for (int i = 0; i < 4; i++) {
      int m = m0 + wr * 64 + i * 16 + (lane >> 4) * 4;
      int bb = m >> 11, srow = m & (S_ - 1);
#pragma unroll
      for (int j = 0; j < 2; j++) {
        int n = n0 + wc * 32 + j * 16 + arow;
        int h = n >> 6, d = n & 63;
        bf16x4 o4;
#pragma unroll
        for (int r = 0; r < 4; r++) o4[r] = (__bf16)acc[i][j][r];
        *reinterpret_cast<bf16x4*>(
            Cvt + ((size_t)(bb * H_ + h) * HD_ + d) * S_ + srow) = o4;
      }
    }
  } else {
#pragma unroll
    for (int i = 0; i < 4; i++) {
#pragma unroll
      for (int j = 0; j < 2; j++) {
#pragma unroll
        for (int r = 0; r < 4; r++) {
          int m = m0 + wr * 64 + i * 16 + (lane >> 4) * 4 + r;
          int n = n0 + wc * 32 + j * 16 + arow;
          float v = acc[i][j][r];
          int bb = m >> 11, srow = m & (S_ - 1);
          int h = n >> 6, d = n & 63;
          size_t oidx = ((size_t)(bb * H_ + h) * S_ + srow) * HD_ + d;
          float other = __shfl_xor(v, 1, 64);   // n bit0 == lane bit0
          int fq = d >> 1;
          float2 cssn = *reinterpret_cast<const float2*>(tab + (srow * 32 + fq) * 2);
          float rv = (d & 1) ? (other * cssn.y + v * cssn.x)
                             : (v * cssn.x - other * cssn.y);
          if (z == 0) rv *= SCL2;   // pre-scale Q: logits in exp2 domain
          ((z == 0) ? Cq : Ck)[oidx] = (__bf16)rv;
        }
      }
    }
  }
}

// ---------------------------------------------------------------------------
// O-projection: tile 128x64, 512-thread / 8-wave blocks. Proven round-11
// kernel, unchanged.
// ---------------------------------------------------------------------------
__global__ __launch_bounds__(512, 4) void gemm_bt0(
    const __bf16* __restrict__ A, const __bf16* __restrict__ W0,
    float* __restrict__ Cf) {
  __shared__ __attribute__((aligned(16))) __bf16 As[128 * 32];
  __shared__ __attribute__((aligned(16))) __bf16 Bs[64 * 32];
  const int tid  = threadIdx.x;
  const int lane = tid & 63;
  const int wv   = tid >> 6;
  const int wr   = wv >> 1;            // 0..3 (M strip of 32)
  const int wc   = wv & 1;             // 0..1 (N strip of 32)
  const int m0 = blockIdx.x * 128;
  const int n0 = blockIdx.y * 64;
  const int arow = lane & 15;
  const int kgrp = (lane >> 4) * 8;

  f32x4 acc[2][2];
#pragma unroll
  for (int i = 0; i < 2; i++)
#pragma unroll
    for (int j = 0; j < 2; j++) acc[i][j] = f32x4{0.f, 0.f, 0.f, 0.f};

  for (int k0 = 0; k0 < 1024; k0 += 32) {
    __syncthreads();
    {
      int c   = wv * 64 + lane;        // 0..511 -> A rows 0..127
      int row = c >> 2;
      int kc  = (c & 3) * 8;
      gload_lds16(A + (size_t)(m0 + row) * 1024 + k0 + kc, As + wv * 512);
      if (wv < 4)                      // 0..255 -> B rows 0..63
        gload_lds16(W0 + (size_t)(n0 + row) * 1024 + k0 + kc, Bs + wv * 512);
    }
    asm volatile("s_waitcnt vmcnt(0)" ::: "memory");
    __syncthreads();
    bf16x8 af[2], bw[2];
#pragma unroll
    for (int i = 0; i < 2; i++)
      af[i] = *reinterpret_cast<const bf16x8*>(As + (wr * 32 + i * 16 + arow) * 32 + kgrp);
#pragma unroll
    for (int j = 0; j < 2; j++)
      bw[j] = *reinterpret_cast<const bf16x8*>(Bs + (wc * 32 + j * 16 + arow) * 32 + kgrp);
#pragma unroll
    for (int i = 0; i < 2; i++)
#pragma unroll
      for (int j = 0; j < 2; j++)
        acc[i][j] = __builtin_amdgcn_mfma_f32_16x16x32_bf16(af[i], bw[j], acc[i][j], 0, 0, 0);
  }

#pragma unroll
  for (int i = 0; i < 2; i++)
#pragma unroll
    for (int j = 0; j < 2; j++)
#pragma unroll
      for (int r = 0; r < 4; r++) {
        int m = m0 + wr * 32 + i * 16 + (lane >> 4) * 4 + r;
        int n = n0 + wc * 32 + j * 16 + arow;
        Cf[(size_t)m * D_ + n] = acc[i][j][r];
      }
}

// ---------------------------------------------------------------------------
// Flash attention, causal. Grid: (bh=32, pr=8). Block: 8 waves x 16 q-rows
// = 128-row Q-tile; paired q-tiles (pr, 15-pr) => uniform 17 kv-iters
// (KVBLK=128). Same per-wave math as the proven round-11 kernel; 2x the
// resident waves per CU (16 = 4/SIMD at 96 VGPR, LDS 64KB x2 = 128KB),
// and each K/V staging serves 128 q-rows (half the K/V traffic).
// Swapped QK^T (P lane-local), key-permuted K, XOR-swizzled K/V LDS via
// pre-swizzled global source, counted vmcnt(4) double-buffer pipeline.
// ---------------------------------------------------------------------------
__global__ __launch_bounds__(512, 2) void attn_kernel(
    const __bf16* __restrict__ Q, const __bf16* __restrict__ K,
    const __bf16* __restrict__ Vt, __bf16* __restrict__ O) {
  __shared__ __attribute__((aligned(16))) __bf16 Ks[2][128 * 64];
  __shared__ __attribute__((aligned(16))) __bf16 Vs[2][64 * 128];
  const int tid = threadIdx.x, lane = tid & 63, wv = tid >> 6;  // wv 0..7
  const int bh = blockIdx.x;   // linear id stride 32 => all pr of a bh share an XCD
  const int pr = blockIdx.y;   // 0..7
  const int b = bh >> 4, h = bh & 15;
  const __bf16* Qb  = Q  + (size_t)bh * S_ * HD_;
  const __bf16* Kb  = K  + (size_t)bh * S_ * HD_;
  const __bf16* Vtb = Vt + (size_t)bh * HD_ * S_;
  const int arow = lane & 15, g = lane >> 4;

  // 4 gload_lds16 per thread per 128-key tile (2 K-chunks + 2 V-chunks)
#define STAGE(K0, BK_, BV_)                                                   \
  do {                                                                        \
    _Pragma("unroll") for (int j = 0; j < 2; ++j) {                           \
      int c = (wv * 2 + j) * 64 + lane;          /* chunk 0..1023 */          \
      int rowk = c >> 3, qqk = c & 7;                                         \
      int qsk = qqk ^ (rowk & 7);                                             \
      int ctp = rowk >> 4, rw = rowk & 15;                                    \
      int kph = ((ctp & 4) << 4) + ((ctp & 2) << 4) + ((ctp & 1) << 2)        \
                + ((rw >> 2) << 3) + (rw & 3);                                \
      gload_lds16(Kb + (size_t)((K0) + kph) * HD_ + qsk * 8,                  \
                  (BK_) + (size_t)(wv * 2 + j) * 512);                        \
      int rowv = c >> 4, qqv = c & 15;                                        \
      int qsv = qqv ^ (rowv & 7);                                             \
      gload_lds16(Vtb + (size_t)rowv * S_ + (K0) + qsv * 8,                   \
                  (BV_) + (size_t)(wv * 2 + j) * 512);                        \
    }                                                                         \
  } while (0)

  for (int seg = 0; seg < 2; ++seg) {
    const int qt = (seg == 0) ? pr : 15 - pr;   // 128-row q-tile index
    const int q0 = qt * 128;
    const int nkv = qt + 1;                     // 128-key tiles
    const int qw = q0 + wv * 16;
    const int qg = qw + arow;                   // this thread's q-row

    bf16x8 aq[2];
#pragma unroll
    for (int j = 0; j < 2; j++)
      aq[j] = *reinterpret_cast<const bf16x8*>(
          Qb + (size_t)(qw + arow) * HD_ + j * 32 + g * 8);

    f32x4 po[4];
#pragma unroll
    for (int dt = 0; dt < 4; dt++) po[dt] = f32x4{0.f, 0.f, 0.f, 0.f};
    float mrow = -1e30f, lrow = 0.f;

    // prologue: stage tiles 0 and 1 (clamped); vmcnt(4) -> tile 0 landed
    STAGE(0, Ks[0], Vs[0]);
    {
      int t1 = (nkv > 1) ? 128 : 0;
      STAGE(t1, Ks[1], Vs[1]);
    }
    asm volatile("s_waitcnt vmcnt(4)" ::: "memory");
    __builtin_amdgcn_s_barrier();

    for (int kt = 0; kt < nkv; ++kt) {
      const int k0 = kt * 128;
      const int cur = kt & 1;
      const __bf16* Kc = Ks[cur];
      const __bf16* Vc = Vs[cur];

      // S^T = K Q^T : D[key][q], 16 MFMA over 128 keys
      f32x4 sc4[8];
      __builtin_amdgcn_s_setprio(1);
#pragma unroll
      for (int ct = 0; ct < 8; ct++) {
        sc4[ct] = f32x4{0.f, 0.f, 0.f, 0.f};
        int L = ct * 16 + arow;
#pragma unroll
        for (int j2 = 0; j2 < 2; j2++) {
          int byt = (L * 128 + j2 * 64 + g * 16) ^ ((L & 7) << 4);
          bf16x8 kb = *reinterpret_cast<const bf16x8*>((const char*)Kc + byt);
          sc4[ct] = __builtin_amdgcn_mfma_f32_16x16x32_bf16(kb, aq[j2], sc4[ct], 0, 0, 0);
        }
      }
      __builtin_amdgcn_s_setprio(0);

      // causal mask (last tile only). physical key of sc4[ct][r]:
      // k0 + (ct&4)*16 + (ct&2)*16 + (ct&1)*4 + g*8 + r
      if (kt == nkv - 1) {
#pragma unroll
        for (int ct = 0; ct < 8; ct++) {
          int kb0 = k0 + ((ct & 4) << 4) + ((ct & 2) << 4) + ((ct & 1) << 2) + g * 8;
#pragma unroll
          for (int r = 0; r < 4; r++)
            if (kb0 + r > qg) sc4[ct][r] = -1e30f;
        }
      }

      // in-register online softmax (one q-row per lane, 32 values)
      float mx = -1e30f;
#pragma unroll
      for (int ct = 0; ct < 8; ct++)
#pragma unroll
        for (int r = 0; r < 4; r++) mx = fmaxf(mx, sc4[ct][r]);
      mx = fmaxf(mx, __shfl_xor(mx, 16, 64));
      mx = fmaxf(mx, __shfl_xor(mx, 32, 64));

      bool noskip = !__all(mx <= mrow + 11.0f);
      if (noskip) {
        float mnew = fmaxf(mrow, mx);
        float corr = fexp2(mrow - mnew);
        mrow = mnew;
        lrow *= corr;
#pragma unroll
        for (int dt = 0; dt < 4; dt++)
#pragma unroll
          for (int r = 0; r < 4; r++) po[dt][r] *= corr;
      }

      float rs = 0.f;
#pragma unroll
      for (int ct = 0; ct < 8; ct++)
#pragma unroll
        for (int r = 0; r < 4; r++) {
          float e = fexp2(sc4[ct][r] - mrow);
          sc4[ct][r] = e;            // overwrite in place (VGPR economy)
          rs += e;
        }
      rs += __shfl_xor(rs, 16, 64);
      rs += __shfl_xor(rs, 32, 64);
      lrow += rs;

      // pack P: pb[jj] holds physical keys jj*32 + g*8 .. +7 (lane-local)
      bf16x8 pb[4];
#pragma unroll
      for (int h2 = 0; h2 < 2; h2++)
#pragma unroll
        for (int j2 = 0; j2 < 2; j2++) {
#pragma unroll
          for (int r = 0; r < 4; r++) {
            pb[h2 * 2 + j2][r]     = (__bf16)sc4[h2 * 4 + 2 * j2][r];
            pb[h2 * 2 + j2][4 + r] = (__bf16)sc4[h2 * 4 + 2 * j2 + 1][r];
          }
        }

      // O^T += V^T P^T : po[dt] = D[d][q], d = dt*16 + g*4 + r, q = arow
      __builtin_amdgcn_s_setprio(1);
#pragma unroll
      for (int dt = 0; dt < 4; dt++) {
        int d = dt * 16 + arow;
#pragma unroll
        for (int jj = 0; jj < 4; jj++) {
          int byv = (d * 256 + jj * 64 + g * 16) ^ ((d & 7) << 4);
          bf16x8 vb = *reinterpret_cast<const bf16x8*>((const char*)Vc + byv);
          po[dt] = __builtin_amdgcn_mfma_f32_16x16x32_bf16(vb, pb[jj], po[dt], 0, 0, 0);
        }
      }
      __builtin_amdgcn_s_setprio(0);

      // pipeline tail: all waves done reading buf[cur], then stage kt+2
      __builtin_amdgcn_s_barrier();
      if (kt < nkv - 1) {
        int nx = kt + 2;
        if (nx > nkv - 1) nx = nkv - 1;       // clamp: uniform 4-load count
        STAGE(nx * 128, Ks[cur], Vs[cur]);    // overwrite retired buffer
        asm volatile("s_waitcnt vmcnt(4)" ::: "memory");  // tile kt+1 landed
      } else {
        asm volatile("s_waitcnt vmcnt(0)" ::: "memory");  // drain for next seg
      }
      __builtin_amdgcn_s_barrier();
    }

    float inv = __builtin_amdgcn_rcpf(lrow);
#pragma unroll
    for (int dt = 0; dt < 4; dt++) {
      bf16x4 o4;
#pragma unroll
      for (int r = 0; r < 4; r++) o4[r] = (__bf16)(po[dt][r] * inv);
      *reinterpret_cast<bf16x4*>(
          O + (size_t)(b * S_ + qg) * D_ + h * HD_ + dt * 16 + g * 4) = o4;
    }
  }
#undef STAGE
}

extern "C" void kernel_launch(void* const* d_in, const int* in_sizes, int n_in,
                              void* d_out, int out_size, void* d_ws, size_t ws_size,
                              hipStream_t stream) {
  const float* x  = (const float*)d_in[0];
  const float* wq = (const float*)d_in[1];
  const float* wk = (const float*)d_in[2];
  const float* wv = (const float*)d_in[3];
  const float* wo = (const float*)d_in[4];
  float* out = (float*)d_out;

  char* w = (char*)d_ws;
  __bf16* xb  = (__bf16*)(w);                    // 8 MB
  __bf16* wqb = (__bf16*)(w + (8u  << 20));      // 2 MB each
  __bf16* wkb = (__bf16*)(w + (10u << 20));
  __bf16* wvb = (__bf16*)(w + (12u << 20));
  __bf16* wob = (__bf16*)(w + (14u << 20));
  __bf16* qws = (__bf16*)(w + (16u << 20));      // 8 MB each
  __bf16* kws = (__bf16*)(w + (24u << 20));
  __bf16* vtw = (__bf16*)(w + (32u << 20));      // V, stored TRANSPOSED [bh][d][s]
  __bf16* aws = (__bf16*)(w + (40u << 20));      // attn out, [token][feature]
  float*  tab = (float*)(w + (48u << 20));       // 512 KB rope table

  cvt_all_kernel<<<8448, 256, 0, stream>>>(x, wq, wk, wv, wo,
                                           xb, wqb, wkb, wvb, wob, tab);
  gemm_qkv<<<dim3(32, 8, 3), 512, 0, stream>>>(xb, wqb, wkb, wvb,
                                               qws, kws, vtw, tab);
  attn_kernel<<<dim3(2 * H_, 8), 512, 0, stream>>>(qws, kws, vtw, aws);
  gemm_bt0<<<dim3(M_ / 128, D_ / 64), 512, 0, stream>>>(aws, wob, out);
}